// Round 15
// baseline (444.771 us; speedup 1.0000x reference)
//
#include <hip/hip_runtime.h>

// RGCNConv: out_i = x_i @ W_root + bias + sum_r mean_{j in N_r(i)} x_j @ W_r
//
// R15: ATOMIC-FREE exact multisplit to 128-seg runs + LDS-sorted aggregate.
//   Evidence: every ~1.6M-global-atomic kernel showed 50-110MB WRITE (R5/R9/
//   R13/R14) - device-scope atomics RMW at the coherent point. So: zero global
//   atomics anywhere in the pipeline.
//   count:  per 4096-edge tile, LDS hist over runs (seg>>7), dense counts row
//   colscan/runscan: counts[t][r] -> exact offsets; runbase[r] via scan
//   place:  LDS rank + exact position, write epack = src | (seg&127)<<24
//   aggregate: block = run; LDS counting-sort of its contiguous edge slice ->
//              in-LDS CSR -> register-accumulated means (4 segs x 8 cols/thread)
//   gemm: R14's mapped-window MFMA (unchanged, validated)

constexpr int D = 128;
constexpr int R = 8;
constexpr int CW = 64;
constexpr int LDA = 40;          // GEMM LDS row stride (80B), conflict-free
constexpr int TILE2 = 4096;      // count/place tile
constexpr int CAP = 3072;        // aggregate chunk capacity (mean run = 2048)
constexpr int MAXRUNS = 8192;

typedef __bf16 bf16x8 __attribute__((ext_vector_type(8)));
typedef float  f32x4  __attribute__((ext_vector_type(4)));
typedef unsigned short u16x8 __attribute__((ext_vector_type(8)));
typedef unsigned short u16x4 __attribute__((ext_vector_type(4)));

__device__ __forceinline__ unsigned short f2bf(float f) {
    unsigned u = __builtin_bit_cast(unsigned, f);
    u += 0x7FFFu + ((u >> 16) & 1u);
    return (unsigned short)(u >> 16);
}
__device__ __forceinline__ float bf2f(unsigned short h) {
    return __builtin_bit_cast(float, (unsigned)h << 16);
}

// ---- x -> bf16 ----
__global__ __launch_bounds__(256)
void xbf_kernel(const float* __restrict__ x, unsigned short* __restrict__ xbf, int nquad) {
    int stride = gridDim.x * 256;
    for (int i = blockIdx.x * 256 + threadIdx.x; i < nquad; i += stride) {
        float4 v = ((const float4*)x)[i];
        u16x4 o;
        o[0] = f2bf(v.x); o[1] = f2bf(v.y); o[2] = f2bf(v.z); o[3] = f2bf(v.w);
        ((u16x4*)xbf)[i] = o;
    }
}

// ---- count: tile t -> counts[t][run] (dense row write, LDS hist only) ----
__global__ __launch_bounds__(256)
void count_kernel(const int* __restrict__ dst, const int* __restrict__ et,
                  int* __restrict__ counts, int E, int nruns) {
    __shared__ int lh[MAXRUNS];
    for (int i = threadIdx.x; i < nruns; i += 256) lh[i] = 0;
    __syncthreads();
    int t0 = blockIdx.x * TILE2;
    #pragma unroll 4
    for (int j = 0; j < TILE2 / 256; ++j) {
        int e = t0 + j * 256 + threadIdx.x;
        if (e < E) {
            int seg = dst[e] * R + et[e];
            atomicAdd(&lh[seg >> 7], 1);
        }
    }
    __syncthreads();
    int* row = counts + (size_t)blockIdx.x * nruns;
    for (int i = threadIdx.x; i < nruns; i += 256) row[i] = lh[i];
}

// ---- colscan: thread r converts counts[:,r] to column prefix, total->runtot ----
__global__ __launch_bounds__(256)
void colscan_kernel(int* __restrict__ counts, int* __restrict__ runtot,
                    int ntiles, int nruns) {
    int r = blockIdx.x * 256 + threadIdx.x;
    if (r >= nruns) return;
    int acc = 0;
    for (int t = 0; t < ntiles; ++t) {
        size_t idx = (size_t)t * nruns + r;
        int v = counts[idx];
        counts[idx] = acc;
        acc += v;
    }
    runtot[r] = acc;
}

// ---- runscan: exclusive scan runtot -> runbase, runbase[nruns] = E ----
__global__ __launch_bounds__(64)
void runscan_kernel(const int* __restrict__ runtot, int* __restrict__ runbase, int nb) {
    int lane = threadIdx.x;
    int carry = 0;
    for (int base = 0; base < nb; base += 64) {
        int i = base + lane;
        int orig = (i < nb) ? runtot[i] : 0;
        int v = orig;
        #pragma unroll
        for (int off = 1; off < 64; off <<= 1) {
            int u = __shfl_up(v, off, 64);
            if (lane >= off) v += u;
        }
        int tot = __shfl(v, 63, 64);
        if (i < nb) runbase[i] = carry + (v - orig);
        carry += tot;
    }
    if (lane == 0) runbase[nb] = carry;
}

// ---- place: exact positions, zero global atomics ----
__global__ __launch_bounds__(256)
void place_kernel(const int* __restrict__ src, const int* __restrict__ dst,
                  const int* __restrict__ et, const int* __restrict__ counts,
                  const int* __restrict__ runbase, unsigned* __restrict__ epack,
                  int E, int nruns) {
    __shared__ int lh[MAXRUNS];
    for (int i = threadIdx.x; i < nruns; i += 256) lh[i] = 0;
    __syncthreads();
    int t0 = blockIdx.x * TILE2;
    const int* colpre = counts + (size_t)blockIdx.x * nruns;
    #pragma unroll 4
    for (int j = 0; j < TILE2 / 256; ++j) {
        int e = t0 + j * 256 + threadIdx.x;
        if (e < E) {
            int seg  = dst[e] * R + et[e];
            int run  = seg >> 7;
            int rank = atomicAdd(&lh[run], 1);          // LDS only
            int pos  = runbase[run] + colpre[run] + rank;
            epack[pos] = (unsigned)src[e] | ((unsigned)(seg & 127) << 24);
        }
    }
}

// ---- aggregate v2: block = run; LDS counting sort -> in-LDS CSR -> reg accum ----
__global__ __launch_bounds__(256)
void aggregate_kernel(const unsigned short* __restrict__ xbf,
                      const unsigned* __restrict__ epack,
                      const int* __restrict__ runbase,
                      unsigned short* __restrict__ mean,
                      int nseg, int c0) {
    __shared__ unsigned raw[CAP];
    __shared__ unsigned srt[CAP];
    __shared__ int hist[128], sc[128], offs[128], cur[128];

    const int tid  = threadIdx.x;
    const int run  = blockIdx.x;
    const int base = runbase[run];
    const int size = runbase[run + 1] - base;
    const int c8   = tid & 7;                 // col octet
    const int sg0  = tid >> 3;                // first seg-in-run (0..31)

    float a[4][8] = {};
    int   cacc[4] = {};

    const int nchunks = (size + CAP - 1) / CAP;
    for (int ch = 0; ch < nchunks; ++ch) {
        int off = ch * CAP;
        int n   = min(CAP, size - off);

        if (tid < 128) hist[tid] = 0;
        __syncthreads();
        // load + hist
        for (int j = tid; j < n; j += 256) {
            unsigned e = epack[base + off + j];
            raw[j] = e;
            atomicAdd(&hist[e >> 24], 1);
        }
        __syncthreads();
        // inclusive scan of hist -> sc
        if (tid < 128) sc[tid] = hist[tid];
        __syncthreads();
        for (int o = 1; o < 128; o <<= 1) {
            int u = 0;
            if (tid < 128 && tid >= o) u = sc[tid - o];
            __syncthreads();
            if (tid < 128) sc[tid] += u;
            __syncthreads();
        }
        if (tid < 128) { int x0 = sc[tid] - hist[tid]; offs[tid] = x0; cur[tid] = x0; }
        __syncthreads();
        // reorder
        for (int j = tid; j < n; j += 256) {
            unsigned e = raw[j];
            int r = atomicAdd(&cur[e >> 24], 1);
            srt[r] = e;
        }
        __syncthreads();
        // accumulate own segs
        #pragma unroll
        for (int i = 0; i < 4; ++i) {
            int s  = sg0 + i * 32;
            int st = offs[s], cn = hist[s];
            cacc[i] += cn;
            for (int k = 0; k < cn; k += 4) {
                unsigned e0 = srt[st + k];
                int s1ok = (k + 1 < cn), s2ok = (k + 2 < cn), s3ok = (k + 3 < cn);
                unsigned e1 = s1ok ? srt[st + k + 1] : 0;
                unsigned e2 = s2ok ? srt[st + k + 2] : 0;
                unsigned e3 = s3ok ? srt[st + k + 3] : 0;
                u16x8 v0 = *(const u16x8*)(xbf + ((size_t)(e0 & 0xFFFFFF) << 7) + c0 + c8 * 8);
                #pragma unroll
                for (int q = 0; q < 8; ++q) a[i][q] += bf2f(v0[q]);
                if (s1ok) {
                    u16x8 v = *(const u16x8*)(xbf + ((size_t)(e1 & 0xFFFFFF) << 7) + c0 + c8 * 8);
                    #pragma unroll
                    for (int q = 0; q < 8; ++q) a[i][q] += bf2f(v[q]);
                }
                if (s2ok) {
                    u16x8 v = *(const u16x8*)(xbf + ((size_t)(e2 & 0xFFFFFF) << 7) + c0 + c8 * 8);
                    #pragma unroll
                    for (int q = 0; q < 8; ++q) a[i][q] += bf2f(v[q]);
                }
                if (s3ok) {
                    u16x8 v = *(const u16x8*)(xbf + ((size_t)(e3 & 0xFFFFFF) << 7) + c0 + c8 * 8);
                    #pragma unroll
                    for (int q = 0; q < 8; ++q) a[i][q] += bf2f(v[q]);
                }
            }
        }
        __syncthreads();   // before next chunk overwrites raw/srt/hist
    }

    // write means
    #pragma unroll
    for (int i = 0; i < 4; ++i) {
        int seg = run * 128 + sg0 + i * 32;
        if (seg < nseg) {
            float inv = (cacc[i] > 0) ? 1.0f / (float)cacc[i] : 0.0f;
            u16x8 o;
            #pragma unroll
            for (int q = 0; q < 8; ++q) o[q] = f2bf(a[i][q] * inv);
            *(u16x8*)(mean + ((size_t)seg << 6) + c8 * 8) = o;
        }
    }
}

// ---- WallTc[n][k] built once ----
__global__ __launch_bounds__(256)
void wallt_kernel(const float* __restrict__ Wroot, const float* __restrict__ W,
                  unsigned short* __restrict__ WallTc) {
    int idx = blockIdx.x * 256 + threadIdx.x;
    if (idx >= 128 * 1152) return;
    int n = idx / 1152, k = idx % 1152;
    float v = (k < 1024) ? W[(size_t)(k >> 7) * 16384 + (size_t)(k & 127) * 128 + n]
                         : Wroot[(size_t)(k - 1024) * 128 + n];
    WallTc[idx] = f2bf(v);
}

// ---- MFMA GEMM (R14, validated): BM=64, mapped k-windows ----
template<bool FIRST>
__global__ __launch_bounds__(256)
void mfma_gemm_kernel(const unsigned short* __restrict__ xbf,
                      const unsigned short* __restrict__ mean,
                      const unsigned short* __restrict__ WallTc,
                      const float* __restrict__ bias,
                      float* __restrict__ out,
                      int N, int c0) {
    constexpr int NT = FIRST ? 20 : 16;
    __shared__ unsigned short As[64 * LDA];
    __shared__ unsigned short Bs[128 * LDA];
    const int tid  = threadIdx.x;
    const int nd0  = blockIdx.x * 64;
    const int lane = tid & 63;
    const int wid  = tid >> 6;
    const int wm   = wid >> 1;
    const int wn   = wid & 1;
    const int arow = tid >> 2;
    const int aoct = tid & 3;
    const int brow = tid >> 1;
    const int bhalf = tid & 1;

    f32x4 acc[2][4] = {};

    const int  anode = nd0 + arow;
    const bool aok   = anode < N;

    for (int kt = 0; kt < NT; ++kt) {
        if (kt) __syncthreads();
        u16x8 av8;
        #pragma unroll
        for (int j = 0; j < 8; ++j) av8[j] = 0;
        int kbase;
        if (FIRST && kt < 4) {
            if (aok)
                av8 = *(const u16x8*)(xbf + ((size_t)anode << 7) + kt * 32 + aoct * 8);
            kbase = 1024 + kt * 32;
        } else {
            int lk = (kt - (FIRST ? 4 : 0)) * 32;
            if (aok)
                av8 = *(const u16x8*)(mean + ((size_t)anode << 9) + lk + aoct * 8);
            kbase = (lk >> 6) * 128 + c0 + (lk & 63);
        }
        const u16x8* wp = (const u16x8*)(WallTc + (size_t)brow * 1152 + kbase + bhalf * 16);
        u16x8 b0 = wp[0], b1 = wp[1];

        *(u16x8*)&As[arow * LDA + aoct * 8]       = av8;
        *(u16x8*)&Bs[brow * LDA + bhalf * 16]     = b0;
        *(u16x8*)&Bs[brow * LDA + bhalf * 16 + 8] = b1;
        __syncthreads();

        const int ko = (lane >> 4) * 8;
        const int rl = lane & 15;
        bf16x8 af[2], bf[4];
        #pragma unroll
        for (int f = 0; f < 2; ++f)
            af[f] = __builtin_bit_cast(bf16x8,
                *(const u16x8*)&As[(wm * 32 + f * 16 + rl) * LDA + ko]);
        #pragma unroll
        for (int f = 0; f < 4; ++f)
            bf[f] = __builtin_bit_cast(bf16x8,
                *(const u16x8*)&Bs[(wn * 64 + f * 16 + rl) * LDA + ko]);
        #pragma unroll
        for (int mf = 0; mf < 2; ++mf)
            #pragma unroll
            for (int nf = 0; nf < 4; ++nf)
                acc[mf][nf] = __builtin_amdgcn_mfma_f32_16x16x32_bf16(af[mf], bf[nf],
                                                                     acc[mf][nf], 0, 0, 0);
    }

    const int rl = lane & 15;
    const int rg = lane >> 4;
    #pragma unroll
    for (int nf = 0; nf < 4; ++nf) {
        int n = wn * 64 + nf * 16 + rl;
        float bb = FIRST ? bias[n] : 0.0f;
        #pragma unroll
        for (int mf = 0; mf < 2; ++mf) {
            #pragma unroll
            for (int i = 0; i < 4; ++i) {
                int nd = nd0 + wm * 32 + mf * 16 + rg * 4 + i;
                if (nd < N) {
                    size_t o = (size_t)nd * 128 + n;
                    if (FIRST) out[o] = acc[mf][nf][i] + bb;
                    else       out[o] += acc[mf][nf][i];
                }
            }
        }
    }
}

extern "C" void kernel_launch(void* const* d_in, const int* in_sizes, int n_in,
                              void* d_out, int out_size, void* d_ws, size_t ws_size,
                              hipStream_t stream) {
    const float* x     = (const float*)d_in[0];
    const float* W     = (const float*)d_in[1];
    const float* Wroot = (const float*)d_in[2];
    const float* bias  = (const float*)d_in[3];
    const int*   ei    = (const int*)d_in[4];
    const int*   et    = (const int*)d_in[5];
    float*       out   = (float*)d_out;

    const int N = in_sizes[0] / D;
    const int E = in_sizes[5];
    const int* src = ei;
    const int* dst = ei + E;

    const int NSEG   = N * R;
    const int NRUNS  = (NSEG + 127) / 128;
    const int NTILES = (E + TILE2 - 1) / TILE2;
    if (NRUNS > MAXRUNS) return;

    const size_t mean_bytes   = (size_t)NSEG * CW * 2;
    const size_t xbf_bytes    = (size_t)N * D * 2;
    const size_t walltc_bytes = (size_t)128 * 1152 * 2;
    const size_t counts_bytes = (size_t)NTILES * NRUNS * 4;
    const size_t need = mean_bytes + xbf_bytes + walltc_bytes + counts_bytes +
                        ((size_t)NRUNS + (NRUNS + 1) + E) * 4 + 256;
    if (ws_size < need) return;

    char* p = (char*)d_ws;
    unsigned short* mean   = (unsigned short*)p;  p += mean_bytes;
    unsigned short* xbf    = (unsigned short*)p;  p += xbf_bytes;
    unsigned short* WallTc = (unsigned short*)p;  p += walltc_bytes;
    int*      counts  = (int*)p;       p += counts_bytes;
    int*      runtot  = (int*)p;       p += (size_t)NRUNS * 4;
    int*      runbase = (int*)p;       p += (size_t)(NRUNS + 1) * 4;
    unsigned* epack   = (unsigned*)p;

    xbf_kernel<<<1024, 256, 0, stream>>>(x, xbf, N * D / 4);
    wallt_kernel<<<(128 * 1152 + 255) / 256, 256, 0, stream>>>(Wroot, W, WallTc);

    count_kernel<<<NTILES, 256, 0, stream>>>(dst, et, counts, E, NRUNS);
    colscan_kernel<<<(NRUNS + 255) / 256, 256, 0, stream>>>(counts, runtot, NTILES, NRUNS);
    runscan_kernel<<<1, 64, 0, stream>>>(runtot, runbase, NRUNS);
    place_kernel<<<NTILES, 256, 0, stream>>>(src, dst, et, counts, runbase, epack, E, NRUNS);

    const int gx = (N + 63) / 64;
    for (int c = 0; c < 2; ++c) {
        int c0 = c * CW;
        aggregate_kernel<<<NRUNS, 256, 0, stream>>>(xbf, epack, runbase, mean, NSEG, c0);
        if (c == 0)
            mfma_gemm_kernel<true><<<gx, 256, 0, stream>>>(
                xbf, mean, WallTc, bias, out, N, c0);
        else
            mfma_gemm_kernel<false><<<gx, 256, 0, stream>>>(
                xbf, mean, WallTc, bias, out, N, c0);
    }
}

// Round 16
// 372.388 us; speedup vs baseline: 1.1944x; 1.1944x over previous
//
#include <hip/hip_runtime.h>

// RGCNConv: out_i = x_i @ W_root + bias + sum_r mean_{j in N_r(i)} x_j @ W_r
//
// R16 = R15 with the colscan parallelism bug fixed (95us @ 1% occupancy ->
// 3-pass hierarchical scan over 32 tile-chunks, ~400-800 blocks each).
// Pipeline (zero global atomics):
//   count:  per 4096-edge tile, LDS hist over runs (seg>>7) -> counts[t][r]
//   colscanA/B/C: hierarchical column prefix -> exact per-(tile,run) offsets
//   runscan: exclusive scan -> runbase
//   place:  LDS rank + exact position, epack = src | (seg&127)<<24
//   aggregate: block = run; LDS counting-sort -> in-LDS CSR -> reg-accum means
//   gemm: R14's mapped-window MFMA (validated)

constexpr int D = 128;
constexpr int R = 8;
constexpr int CW = 64;
constexpr int LDA = 40;          // GEMM LDS row stride (80B), conflict-free
constexpr int TILE2 = 4096;      // count/place tile
constexpr int CAP = 3072;        // aggregate chunk capacity
constexpr int MAXRUNS = 8192;
constexpr int TCH = 32;          // tile chunks for hierarchical colscan

typedef __bf16 bf16x8 __attribute__((ext_vector_type(8)));
typedef float  f32x4  __attribute__((ext_vector_type(4)));
typedef unsigned short u16x8 __attribute__((ext_vector_type(8)));
typedef unsigned short u16x4 __attribute__((ext_vector_type(4)));

__device__ __forceinline__ unsigned short f2bf(float f) {
    unsigned u = __builtin_bit_cast(unsigned, f);
    u += 0x7FFFu + ((u >> 16) & 1u);
    return (unsigned short)(u >> 16);
}
__device__ __forceinline__ float bf2f(unsigned short h) {
    return __builtin_bit_cast(float, (unsigned)h << 16);
}

// ---- x -> bf16 ----
__global__ __launch_bounds__(256)
void xbf_kernel(const float* __restrict__ x, unsigned short* __restrict__ xbf, int nquad) {
    int stride = gridDim.x * 256;
    for (int i = blockIdx.x * 256 + threadIdx.x; i < nquad; i += stride) {
        float4 v = ((const float4*)x)[i];
        u16x4 o;
        o[0] = f2bf(v.x); o[1] = f2bf(v.y); o[2] = f2bf(v.z); o[3] = f2bf(v.w);
        ((u16x4*)xbf)[i] = o;
    }
}

// ---- count: tile t -> counts[t][run] ----
__global__ __launch_bounds__(256)
void count_kernel(const int* __restrict__ dst, const int* __restrict__ et,
                  int* __restrict__ counts, int E, int nruns) {
    __shared__ int lh[MAXRUNS];
    for (int i = threadIdx.x; i < nruns; i += 256) lh[i] = 0;
    __syncthreads();
    int t0 = blockIdx.x * TILE2;
    #pragma unroll 4
    for (int j = 0; j < TILE2 / 256; ++j) {
        int e = t0 + j * 256 + threadIdx.x;
        if (e < E) {
            int seg = dst[e] * R + et[e];
            atomicAdd(&lh[seg >> 7], 1);
        }
    }
    __syncthreads();
    int* row = counts + (size_t)blockIdx.x * nruns;
    for (int i = threadIdx.x; i < nruns; i += 256) row[i] = lh[i];
}

// ---- colscan A: partial sums per (chunk, run) ----
__global__ __launch_bounds__(256)
void colscanA_kernel(const int* __restrict__ counts, int* __restrict__ part,
                     int ntiles, int nruns, int cpt) {
    int r = blockIdx.x * 256 + threadIdx.x;
    int c = blockIdx.y;
    if (r >= nruns) return;
    int t0 = c * cpt, t1 = min(t0 + cpt, ntiles);
    int acc = 0;
    for (int t = t0; t < t1; ++t) acc += counts[(size_t)t * nruns + r];
    part[(size_t)c * nruns + r] = acc;
}

// ---- colscan B: scan partials across chunks; emit runtot ----
__global__ __launch_bounds__(256)
void colscanB_kernel(int* __restrict__ part, int* __restrict__ runtot,
                     int nchunks, int nruns) {
    int r = blockIdx.x * 256 + threadIdx.x;
    if (r >= nruns) return;
    int acc = 0;
    for (int c = 0; c < nchunks; ++c) {
        size_t i = (size_t)c * nruns + r;
        int v = part[i];
        part[i] = acc;
        acc += v;
    }
    runtot[r] = acc;
}

// ---- colscan C: in-chunk running prefix seeded by chunk base ----
__global__ __launch_bounds__(256)
void colscanC_kernel(int* __restrict__ counts, const int* __restrict__ part,
                     int ntiles, int nruns, int cpt) {
    int r = blockIdx.x * 256 + threadIdx.x;
    int c = blockIdx.y;
    if (r >= nruns) return;
    int t0 = c * cpt, t1 = min(t0 + cpt, ntiles);
    int acc = part[(size_t)c * nruns + r];
    for (int t = t0; t < t1; ++t) {
        size_t i = (size_t)t * nruns + r;
        int v = counts[i];
        counts[i] = acc;
        acc += v;
    }
}

// ---- runscan: exclusive scan runtot -> runbase, runbase[nruns] = E ----
__global__ __launch_bounds__(64)
void runscan_kernel(const int* __restrict__ runtot, int* __restrict__ runbase, int nb) {
    int lane = threadIdx.x;
    int carry = 0;
    for (int base = 0; base < nb; base += 64) {
        int i = base + lane;
        int orig = (i < nb) ? runtot[i] : 0;
        int v = orig;
        #pragma unroll
        for (int off = 1; off < 64; off <<= 1) {
            int u = __shfl_up(v, off, 64);
            if (lane >= off) v += u;
        }
        int tot = __shfl(v, 63, 64);
        if (i < nb) runbase[i] = carry + (v - orig);
        carry += tot;
    }
    if (lane == 0) runbase[nb] = carry;
}

// ---- place: exact positions, zero global atomics ----
__global__ __launch_bounds__(256)
void place_kernel(const int* __restrict__ src, const int* __restrict__ dst,
                  const int* __restrict__ et, const int* __restrict__ counts,
                  const int* __restrict__ runbase, unsigned* __restrict__ epack,
                  int E, int nruns) {
    __shared__ int lh[MAXRUNS];
    for (int i = threadIdx.x; i < nruns; i += 256) lh[i] = 0;
    __syncthreads();
    int t0 = blockIdx.x * TILE2;
    const int* colpre = counts + (size_t)blockIdx.x * nruns;
    #pragma unroll 4
    for (int j = 0; j < TILE2 / 256; ++j) {
        int e = t0 + j * 256 + threadIdx.x;
        if (e < E) {
            int seg  = dst[e] * R + et[e];
            int run  = seg >> 7;
            int rank = atomicAdd(&lh[run], 1);          // LDS only
            int pos  = runbase[run] + colpre[run] + rank;
            epack[pos] = (unsigned)src[e] | ((unsigned)(seg & 127) << 24);
        }
    }
}

// ---- aggregate: block = run; LDS counting sort -> in-LDS CSR -> reg accum ----
__global__ __launch_bounds__(256)
void aggregate_kernel(const unsigned short* __restrict__ xbf,
                      const unsigned* __restrict__ epack,
                      const int* __restrict__ runbase,
                      unsigned short* __restrict__ mean,
                      int nseg, int c0) {
    __shared__ unsigned raw[CAP];
    __shared__ unsigned srt[CAP];
    __shared__ int hist[128], sc[128], offs[128], cur[128];

    const int tid  = threadIdx.x;
    const int run  = blockIdx.x;
    const int base = runbase[run];
    const int size = runbase[run + 1] - base;
    const int c8   = tid & 7;
    const int sg0  = tid >> 3;

    float a[4][8] = {};
    int   cacc[4] = {};

    const int nchunks = (size + CAP - 1) / CAP;
    for (int ch = 0; ch < nchunks; ++ch) {
        int off = ch * CAP;
        int n   = min(CAP, size - off);

        if (tid < 128) hist[tid] = 0;
        __syncthreads();
        for (int j = tid; j < n; j += 256) {
            unsigned e = epack[base + off + j];
            raw[j] = e;
            atomicAdd(&hist[e >> 24], 1);
        }
        __syncthreads();
        if (tid < 128) sc[tid] = hist[tid];
        __syncthreads();
        for (int o = 1; o < 128; o <<= 1) {
            int u = 0;
            if (tid < 128 && tid >= o) u = sc[tid - o];
            __syncthreads();
            if (tid < 128) sc[tid] += u;
            __syncthreads();
        }
        if (tid < 128) { int x0 = sc[tid] - hist[tid]; offs[tid] = x0; cur[tid] = x0; }
        __syncthreads();
        for (int j = tid; j < n; j += 256) {
            unsigned e = raw[j];
            int r = atomicAdd(&cur[e >> 24], 1);
            srt[r] = e;
        }
        __syncthreads();
        #pragma unroll
        for (int i = 0; i < 4; ++i) {
            int s  = sg0 + i * 32;
            int st = offs[s], cn = hist[s];
            cacc[i] += cn;
            for (int k = 0; k < cn; k += 4) {
                unsigned e0 = srt[st + k];
                int s1ok = (k + 1 < cn), s2ok = (k + 2 < cn), s3ok = (k + 3 < cn);
                unsigned e1 = s1ok ? srt[st + k + 1] : 0;
                unsigned e2 = s2ok ? srt[st + k + 2] : 0;
                unsigned e3 = s3ok ? srt[st + k + 3] : 0;
                u16x8 v0 = *(const u16x8*)(xbf + ((size_t)(e0 & 0xFFFFFF) << 7) + c0 + c8 * 8);
                #pragma unroll
                for (int q = 0; q < 8; ++q) a[i][q] += bf2f(v0[q]);
                if (s1ok) {
                    u16x8 v = *(const u16x8*)(xbf + ((size_t)(e1 & 0xFFFFFF) << 7) + c0 + c8 * 8);
                    #pragma unroll
                    for (int q = 0; q < 8; ++q) a[i][q] += bf2f(v[q]);
                }
                if (s2ok) {
                    u16x8 v = *(const u16x8*)(xbf + ((size_t)(e2 & 0xFFFFFF) << 7) + c0 + c8 * 8);
                    #pragma unroll
                    for (int q = 0; q < 8; ++q) a[i][q] += bf2f(v[q]);
                }
                if (s3ok) {
                    u16x8 v = *(const u16x8*)(xbf + ((size_t)(e3 & 0xFFFFFF) << 7) + c0 + c8 * 8);
                    #pragma unroll
                    for (int q = 0; q < 8; ++q) a[i][q] += bf2f(v[q]);
                }
            }
        }
        __syncthreads();
    }

    #pragma unroll
    for (int i = 0; i < 4; ++i) {
        int seg = run * 128 + sg0 + i * 32;
        if (seg < nseg) {
            float inv = (cacc[i] > 0) ? 1.0f / (float)cacc[i] : 0.0f;
            u16x8 o;
            #pragma unroll
            for (int q = 0; q < 8; ++q) o[q] = f2bf(a[i][q] * inv);
            *(u16x8*)(mean + ((size_t)seg << 6) + c8 * 8) = o;
        }
    }
}

// ---- WallTc[n][k] built once ----
__global__ __launch_bounds__(256)
void wallt_kernel(const float* __restrict__ Wroot, const float* __restrict__ W,
                  unsigned short* __restrict__ WallTc) {
    int idx = blockIdx.x * 256 + threadIdx.x;
    if (idx >= 128 * 1152) return;
    int n = idx / 1152, k = idx % 1152;
    float v = (k < 1024) ? W[(size_t)(k >> 7) * 16384 + (size_t)(k & 127) * 128 + n]
                         : Wroot[(size_t)(k - 1024) * 128 + n];
    WallTc[idx] = f2bf(v);
}

// ---- MFMA GEMM (validated): BM=64, mapped k-windows ----
template<bool FIRST>
__global__ __launch_bounds__(256)
void mfma_gemm_kernel(const unsigned short* __restrict__ xbf,
                      const unsigned short* __restrict__ mean,
                      const unsigned short* __restrict__ WallTc,
                      const float* __restrict__ bias,
                      float* __restrict__ out,
                      int N, int c0) {
    constexpr int NT = FIRST ? 20 : 16;
    __shared__ unsigned short As[64 * LDA];
    __shared__ unsigned short Bs[128 * LDA];
    const int tid  = threadIdx.x;
    const int nd0  = blockIdx.x * 64;
    const int lane = tid & 63;
    const int wid  = tid >> 6;
    const int wm   = wid >> 1;
    const int wn   = wid & 1;
    const int arow = tid >> 2;
    const int aoct = tid & 3;
    const int brow = tid >> 1;
    const int bhalf = tid & 1;

    f32x4 acc[2][4] = {};

    const int  anode = nd0 + arow;
    const bool aok   = anode < N;

    for (int kt = 0; kt < NT; ++kt) {
        if (kt) __syncthreads();
        u16x8 av8;
        #pragma unroll
        for (int j = 0; j < 8; ++j) av8[j] = 0;
        int kbase;
        if (FIRST && kt < 4) {
            if (aok)
                av8 = *(const u16x8*)(xbf + ((size_t)anode << 7) + kt * 32 + aoct * 8);
            kbase = 1024 + kt * 32;
        } else {
            int lk = (kt - (FIRST ? 4 : 0)) * 32;
            if (aok)
                av8 = *(const u16x8*)(mean + ((size_t)anode << 9) + lk + aoct * 8);
            kbase = (lk >> 6) * 128 + c0 + (lk & 63);
        }
        const u16x8* wp = (const u16x8*)(WallTc + (size_t)brow * 1152 + kbase + bhalf * 16);
        u16x8 b0 = wp[0], b1 = wp[1];

        *(u16x8*)&As[arow * LDA + aoct * 8]       = av8;
        *(u16x8*)&Bs[brow * LDA + bhalf * 16]     = b0;
        *(u16x8*)&Bs[brow * LDA + bhalf * 16 + 8] = b1;
        __syncthreads();

        const int ko = (lane >> 4) * 8;
        const int rl = lane & 15;
        bf16x8 af[2], bf[4];
        #pragma unroll
        for (int f = 0; f < 2; ++f)
            af[f] = __builtin_bit_cast(bf16x8,
                *(const u16x8*)&As[(wm * 32 + f * 16 + rl) * LDA + ko]);
        #pragma unroll
        for (int f = 0; f < 4; ++f)
            bf[f] = __builtin_bit_cast(bf16x8,
                *(const u16x8*)&Bs[(wn * 64 + f * 16 + rl) * LDA + ko]);
        #pragma unroll
        for (int mf = 0; mf < 2; ++mf)
            #pragma unroll
            for (int nf = 0; nf < 4; ++nf)
                acc[mf][nf] = __builtin_amdgcn_mfma_f32_16x16x32_bf16(af[mf], bf[nf],
                                                                     acc[mf][nf], 0, 0, 0);
    }

    const int rl = lane & 15;
    const int rg = lane >> 4;
    #pragma unroll
    for (int nf = 0; nf < 4; ++nf) {
        int n = wn * 64 + nf * 16 + rl;
        float bb = FIRST ? bias[n] : 0.0f;
        #pragma unroll
        for (int mf = 0; mf < 2; ++mf) {
            #pragma unroll
            for (int i = 0; i < 4; ++i) {
                int nd = nd0 + wm * 32 + mf * 16 + rg * 4 + i;
                if (nd < N) {
                    size_t o = (size_t)nd * 128 + n;
                    if (FIRST) out[o] = acc[mf][nf][i] + bb;
                    else       out[o] += acc[mf][nf][i];
                }
            }
        }
    }
}

extern "C" void kernel_launch(void* const* d_in, const int* in_sizes, int n_in,
                              void* d_out, int out_size, void* d_ws, size_t ws_size,
                              hipStream_t stream) {
    const float* x     = (const float*)d_in[0];
    const float* W     = (const float*)d_in[1];
    const float* Wroot = (const float*)d_in[2];
    const float* bias  = (const float*)d_in[3];
    const int*   ei    = (const int*)d_in[4];
    const int*   et    = (const int*)d_in[5];
    float*       out   = (float*)d_out;

    const int N = in_sizes[0] / D;
    const int E = in_sizes[5];
    const int* src = ei;
    const int* dst = ei + E;

    const int NSEG   = N * R;
    const int NRUNS  = (NSEG + 127) / 128;
    const int NTILES = (E + TILE2 - 1) / TILE2;
    if (NRUNS > MAXRUNS) return;

    const size_t mean_bytes   = (size_t)NSEG * CW * 2;
    const size_t xbf_bytes    = (size_t)N * D * 2;
    const size_t walltc_bytes = (size_t)128 * 1152 * 2;
    const size_t counts_bytes = (size_t)NTILES * NRUNS * 4;
    const size_t part_bytes   = (size_t)TCH * NRUNS * 4;
    const size_t need = mean_bytes + xbf_bytes + walltc_bytes + counts_bytes +
                        part_bytes + ((size_t)NRUNS + (NRUNS + 1) + E) * 4 + 256;
    if (ws_size < need) return;

    char* p = (char*)d_ws;
    unsigned short* mean   = (unsigned short*)p;  p += mean_bytes;
    unsigned short* xbf    = (unsigned short*)p;  p += xbf_bytes;
    unsigned short* WallTc = (unsigned short*)p;  p += walltc_bytes;
    int*      counts  = (int*)p;       p += counts_bytes;
    int*      part    = (int*)p;       p += part_bytes;
    int*      runtot  = (int*)p;       p += (size_t)NRUNS * 4;
    int*      runbase = (int*)p;       p += (size_t)(NRUNS + 1) * 4;
    unsigned* epack   = (unsigned*)p;

    xbf_kernel<<<1024, 256, 0, stream>>>(x, xbf, N * D / 4);
    wallt_kernel<<<(128 * 1152 + 255) / 256, 256, 0, stream>>>(Wroot, W, WallTc);

    count_kernel<<<NTILES, 256, 0, stream>>>(dst, et, counts, E, NRUNS);

    const int cpt = (NTILES + TCH - 1) / TCH;
    dim3 cgrid((NRUNS + 255) / 256, TCH);
    colscanA_kernel<<<cgrid, 256, 0, stream>>>(counts, part, NTILES, NRUNS, cpt);
    colscanB_kernel<<<(NRUNS + 255) / 256, 256, 0, stream>>>(part, runtot, TCH, NRUNS);
    colscanC_kernel<<<cgrid, 256, 0, stream>>>(counts, part, NTILES, NRUNS, cpt);
    runscan_kernel<<<1, 64, 0, stream>>>(runtot, runbase, NRUNS);

    place_kernel<<<NTILES, 256, 0, stream>>>(src, dst, et, counts, runbase, epack, E, NRUNS);

    const int gx = (N + 63) / 64;
    for (int c = 0; c < 2; ++c) {
        int c0 = c * CW;
        aggregate_kernel<<<NRUNS, 256, 0, stream>>>(xbf, epack, runbase, mean, NSEG, c0);
        if (c == 0)
            mfma_gemm_kernel<true><<<gx, 256, 0, stream>>>(
                xbf, mean, WallTc, bias, out, N, c0);
        else
            mfma_gemm_kernel<false><<<gx, 256, 0, stream>>>(
                xbf, mean, WallTc, bias, out, N, c0);
    }
}